// Round 1
// baseline (328.684 us; speedup 1.0000x reference)
//
#include <hip/hip_runtime.h>
#include <stdint.h>

#define HIDDEN 1024
#define HEADS 16
#define HEAD_DIM 64
#define BATCH 4
#define SEQ 2048
#define ROWS (BATCH * SEQ) /* 8192 */

typedef float f32x4 __attribute__((ext_vector_type(4)));
typedef short bf16x8 __attribute__((ext_vector_type(8))); // 8 bf16 = 4 VGPRs

__device__ __forceinline__ uint16_t f32_to_bf16_rne(float f) {
    uint32_t u = __float_as_uint(f);
    uint32_t r = u + 0x7FFFu + ((u >> 16) & 1u);
    return (uint16_t)(r >> 16);
}
__device__ __forceinline__ float bf16_to_f32(uint16_t u) {
    return __uint_as_float(((uint32_t)u) << 16);
}

// ---------------------------------------------------------------------------
// Kernel 1: W[K][N] fp32  ->  Wt[N][K] bf16 (per z in {q,k,v})
// ---------------------------------------------------------------------------
__global__ __launch_bounds__(256) void wt_kernel(const float* __restrict__ Wq,
                                                 const float* __restrict__ Wk,
                                                 const float* __restrict__ Wv,
                                                 uint16_t* __restrict__ Wt) {
    const float* W = blockIdx.z == 0 ? Wq : (blockIdx.z == 1 ? Wk : Wv);
    uint16_t* out = Wt + (size_t)blockIdx.z * HIDDEN * HIDDEN;
    __shared__ float tile[64][65];
    int k0 = blockIdx.x * 64, n0 = blockIdx.y * 64;
    int r = threadIdx.x >> 6, c = threadIdx.x & 63;
    for (int it = 0; it < 16; ++it) {
        int rr = r + 4 * it;
        tile[rr][c] = W[(size_t)(k0 + rr) * HIDDEN + n0 + c];
    }
    __syncthreads();
    for (int it = 0; it < 16; ++it) {
        int rr = r + 4 * it;
        out[(size_t)(n0 + rr) * HIDDEN + k0 + c] = f32_to_bf16_rne(tile[c][rr]);
    }
}

// ---------------------------------------------------------------------------
// Kernel 2: zero the KtV accumulator (ws is poisoned 0xAA each launch)
// ---------------------------------------------------------------------------
__global__ __launch_bounds__(256) void zero_kernel(float4* __restrict__ p) {
    int i = blockIdx.x * 256 + threadIdx.x;
    p[i] = make_float4(0.f, 0.f, 0.f, 0.f);
}

// ---------------------------------------------------------------------------
// Kernel 3: projection GEMM  out[z] = X[z] @ W[z] + b[z]   (bf16 MFMA)
//   X fp32 [8192][1024], Wt bf16 [1024(N)][1024(K)], out bf16 [8192][1024]
//   Tile 128x128, BK=64, 4 waves (2x2 of 64x64), mfma 16x16x32.
//   LDS layout: 16B chunks XOR-swizzled: physical chunk p = logical c ^ (row&7)
//   -> conflict-free ds_read_b128 frag loads AND contiguous global_load_lds dest.
// ---------------------------------------------------------------------------
__global__ __launch_bounds__(256) void proj_gemm(const float* __restrict__ Xq,
                                                 const float* __restrict__ Xk,
                                                 const float* __restrict__ Xv,
                                                 const uint16_t* __restrict__ Wt,
                                                 const float* __restrict__ Bq,
                                                 const float* __restrict__ Bk,
                                                 const float* __restrict__ Bv,
                                                 uint16_t* __restrict__ QKV) {
    const int z = blockIdx.z;
    const float* X = z == 0 ? Xq : (z == 1 ? Xk : Xv);
    const float* bias = z == 0 ? Bq : (z == 1 ? Bk : Bv);
    const uint16_t* W = Wt + (size_t)z * HIDDEN * HIDDEN;
    uint16_t* out = QKV + (size_t)z * ROWS * HIDDEN;

    __shared__ uint16_t lds[16384]; // A: [0,8192) elems, B: [8192,16384)

    const int tid = threadIdx.x;
    const int lane = tid & 63;
    const int w = tid >> 6;
    const int wm = (w >> 1) * 64;
    const int wn = (w & 1) * 64;
    const int m_lane = lane & 15;
    const int kq = lane >> 4;
    const int m0 = blockIdx.x * 128;
    const int n0 = blockIdx.y * 128;

    f32x4 acc[4][4] = {};

    for (int kb = 0; kb < HIDDEN; kb += 64) {
        // ---- stage B (bf16 weights) via async global->LDS, 4 insts/wave ----
        for (int t = 0; t < 4; ++t) {
            int gbase = (w * 4 + t) * 64;         // chunk index of lane 0
            int g = gbase + lane;                 // this lane's chunk
            int nr = g >> 3;                      // LDS row (n)
            int c = (g & 7) ^ (nr & 7);           // logical k-chunk to fetch
            const uint16_t* src = W + (size_t)(n0 + nr) * HIDDEN + kb + c * 8;
            __builtin_amdgcn_global_load_lds(
                (const __attribute__((address_space(1))) uint32_t*)src,
                (__attribute__((address_space(3))) uint32_t*)(&lds[8192 + gbase * 8]),
                16, 0, 0);
        }
        // ---- stage A (fp32 -> bf16 via VALU), 4 chunks/thread ----
        for (int t = 0; t < 4; ++t) {
            int g = t * 256 + tid;                // 0..1023
            int r = g >> 3;
            int p = g & 7;
            int c = p ^ (r & 7);
            const float* src = X + (size_t)(m0 + r) * HIDDEN + kb + c * 8;
            float4 f0 = *(const float4*)(src);
            float4 f1 = *(const float4*)(src + 4);
            uint4 pk;
            pk.x = (uint32_t)f32_to_bf16_rne(f0.x) | ((uint32_t)f32_to_bf16_rne(f0.y) << 16);
            pk.y = (uint32_t)f32_to_bf16_rne(f0.z) | ((uint32_t)f32_to_bf16_rne(f0.w) << 16);
            pk.z = (uint32_t)f32_to_bf16_rne(f1.x) | ((uint32_t)f32_to_bf16_rne(f1.y) << 16);
            pk.w = (uint32_t)f32_to_bf16_rne(f1.z) | ((uint32_t)f32_to_bf16_rne(f1.w) << 16);
            *(uint4*)(&lds[g * 8]) = pk;
        }
        __syncthreads();
        // ---- compute: 2 k-steps x 16 MFMA/wave ----
        for (int ks = 0; ks < 2; ++ks) {
            int cbase = ks * 4 + kq; // logical chunk for this lane's k-slice
            bf16x8 af[4], bfr[4];
            for (int i = 0; i < 4; ++i) {
                int r = wm + i * 16 + m_lane;
                int p = cbase ^ (r & 7);
                af[i] = *(const bf16x8*)(&lds[r * 64 + p * 8]);
            }
            for (int j = 0; j < 4; ++j) {
                int nr = wn + j * 16 + m_lane;
                int p = cbase ^ (nr & 7);
                bfr[j] = *(const bf16x8*)(&lds[8192 + nr * 64 + p * 8]);
            }
            for (int i = 0; i < 4; ++i)
                for (int j = 0; j < 4; ++j)
                    acc[i][j] = __builtin_amdgcn_mfma_f32_16x16x32_bf16(
                        af[i], bfr[j], acc[i][j], 0, 0, 0);
        }
        __syncthreads();
    }

    // ---- epilogue: +bias, store bf16. C/D: col=lane&15, row=(lane>>4)*4+reg ----
    for (int j = 0; j < 4; ++j) {
        int col = n0 + wn + j * 16 + m_lane;
        float bj = bias[col];
        for (int i = 0; i < 4; ++i) {
            int rbase = m0 + wm + i * 16 + kq * 4;
            for (int rg = 0; rg < 4; ++rg) {
                float v = acc[i][j][rg] + bj;
                out[(size_t)(rbase + rg) * HIDDEN + col] = f32_to_bf16_rne(v);
            }
        }
    }
}

// ---------------------------------------------------------------------------
// Kernel 4: M'[bh] += (1/8) * K_h^T V_h  over a 128-row S chunk (atomicAdd)
// ---------------------------------------------------------------------------
__global__ __launch_bounds__(256) void kv_kernel(const uint16_t* __restrict__ K,
                                                 const uint16_t* __restrict__ V,
                                                 float* __restrict__ M) {
    const int bh = blockIdx.x;  // b*16+h
    const int sc = blockIdx.y;  // 0..15
    const int b = bh >> 4, h = bh & 15;
    const int tid = threadIdx.x;
    const size_t rowbase = ((size_t)b * SEQ + sc * 128) * HIDDEN + h * 64;

    __shared__ float kk[8][64];
    __shared__ float vv[8][64];
    float acc[4][4] = {};
    const int i0 = (tid >> 4) * 4, j0 = (tid & 15) * 4;

    for (int batch = 0; batch < 16; ++batch) {
        __syncthreads();
        for (int t = 0; t < 2; ++t) {
            int e = t * 256 + tid; // 0..511
            int r = e >> 6, c = e & 63;
            size_t g = rowbase + (size_t)(batch * 8 + r) * HIDDEN + c;
            kk[r][c] = bf16_to_f32(K[g]);
            vv[r][c] = bf16_to_f32(V[g]);
        }
        __syncthreads();
        for (int r = 0; r < 8; ++r) {
            f32x4 ka = *(const f32x4*)(&kk[r][i0]);
            f32x4 va = *(const f32x4*)(&vv[r][j0]);
            for (int a = 0; a < 4; ++a)
                for (int bb = 0; bb < 4; ++bb)
                    acc[a][bb] += ka[a] * va[bb];
        }
    }
    float* Mh = M + (size_t)bh * 4096;
    for (int a = 0; a < 4; ++a)
        for (int bb = 0; bb < 4; ++bb)
            atomicAdd(&Mh[(i0 + a) * 64 + j0 + bb], acc[a][bb] * 0.125f);
}

// ---------------------------------------------------------------------------
// Kernel 5: out[b, s, h*64+j] = sum_i Q[b,s,h*64+i] * M'[bh][i][j]   (fp32)
// ---------------------------------------------------------------------------
__global__ __launch_bounds__(256) void ctx_kernel(const uint16_t* __restrict__ Q,
                                                  const float* __restrict__ M,
                                                  float* __restrict__ out) {
    const int bh = blockIdx.x;
    const int sc = blockIdx.y;
    const int b = bh >> 4, h = bh & 15;
    const int tid = threadIdx.x;

    __shared__ float Mh[64][64]; // 16 KB
    __shared__ float qq[16][64]; // 4 KB
    const float* Msrc = M + (size_t)bh * 4096;
    for (int t = 0; t < 16; ++t)
        ((float*)Mh)[t * 256 + tid] = Msrc[t * 256 + tid];

    const size_t rowbase = ((size_t)b * SEQ + sc * 128) * HIDDEN + h * 64;
    const int tr = tid >> 4, j0 = (tid & 15) * 4;

    for (int batch = 0; batch < 8; ++batch) {
        __syncthreads();
        for (int t = 0; t < 4; ++t) {
            int e = t * 256 + tid; // 0..1023
            int r = e >> 6, c = e & 63;
            qq[r][c] = bf16_to_f32(Q[rowbase + (size_t)(batch * 16 + r) * HIDDEN + c]);
        }
        __syncthreads();
        f32x4 a = {0.f, 0.f, 0.f, 0.f};
        for (int i = 0; i < 64; ++i) {
            float qv = qq[tr][i];
            f32x4 m4 = *(const f32x4*)(&Mh[i][j0]);
            a += qv * m4;
        }
        *(f32x4*)(out + rowbase + (size_t)(batch * 16 + tr) * HIDDEN + j0) = a;
    }
}

// ---------------------------------------------------------------------------
extern "C" void kernel_launch(void* const* d_in, const int* in_sizes, int n_in,
                              void* d_out, int out_size, void* d_ws, size_t ws_size,
                              hipStream_t stream) {
    const float* Xq = (const float*)d_in[0];
    const float* Xk = (const float*)d_in[1];
    const float* Xv = (const float*)d_in[2];
    const float* Wq = (const float*)d_in[3];
    const float* Bq = (const float*)d_in[4];
    const float* Wk = (const float*)d_in[5];
    const float* Bk = (const float*)d_in[6];
    const float* Wv = (const float*)d_in[7];
    const float* Bv = (const float*)d_in[8];
    float* out = (float*)d_out;

    char* ws = (char*)d_ws;
    uint16_t* Wt = (uint16_t*)ws;                            // 3 * 2 MiB = 6,291,456 B
    uint16_t* QKV = (uint16_t*)(ws + 6291456);               // 3 * 16 MiB = 50,331,648 B
    float* M = (float*)(ws + 6291456 + 50331648);            // 1,048,576 B  (total ~57.7 MB)

    wt_kernel<<<dim3(16, 16, 3), 256, 0, stream>>>(Wq, Wk, Wv, Wt);
    zero_kernel<<<dim3(256), 256, 0, stream>>>((float4*)M);
    proj_gemm<<<dim3(64, 8, 3), 256, 0, stream>>>(Xq, Xk, Xv, Wt, Bq, Bk, Bv, QKV);

    const uint16_t* Qp = QKV;
    const uint16_t* Kp = QKV + (size_t)ROWS * HIDDEN;
    const uint16_t* Vp = QKV + 2 * (size_t)ROWS * HIDDEN;
    kv_kernel<<<dim3(64, 16), 256, 0, stream>>>(Kp, Vp, M);
    ctx_kernel<<<dim3(64, 16), 256, 0, stream>>>(Qp, M, out);
}

// Round 2
// 311.416 us; speedup vs baseline: 1.0555x; 1.0555x over previous
//
#include <hip/hip_runtime.h>
#include <stdint.h>

#define HIDDEN 1024
#define HEADS 16
#define HEAD_DIM 64
#define BATCH 4
#define SEQ 2048
#define ROWS (BATCH * SEQ) /* 8192 */

typedef float f32x4 __attribute__((ext_vector_type(4)));
typedef short bf16x8 __attribute__((ext_vector_type(8))); // 8 bf16 = 4 VGPRs

__device__ __forceinline__ uint16_t f32_to_bf16_rne(float f) {
    uint32_t u = __float_as_uint(f);
    uint32_t r = u + 0x7FFFu + ((u >> 16) & 1u);
    return (uint16_t)(r >> 16);
}
__device__ __forceinline__ float bf16_to_f32(uint16_t u) {
    return __uint_as_float(((uint32_t)u) << 16);
}

// ---------------------------------------------------------------------------
// Kernel 0: convert X (q,k,v inputs) fp32 -> bf16, streaming.
// grid.x = 3 * 4096 blocks, 2048 elems/block.
// ---------------------------------------------------------------------------
__global__ __launch_bounds__(256) void cvt_kernel(const float* __restrict__ Xq,
                                                  const float* __restrict__ Xk,
                                                  const float* __restrict__ Xv,
                                                  uint16_t* __restrict__ Xb) {
    int z = blockIdx.x >> 12;
    const float* X = z == 0 ? Xq : (z == 1 ? Xk : Xv);
    uint16_t* out = Xb + (size_t)z * ROWS * HIDDEN;
    size_t e = ((size_t)(blockIdx.x & 4095) * 256 + threadIdx.x) * 8;
    float4 f0 = *(const float4*)(X + e);
    float4 f1 = *(const float4*)(X + e + 4);
    uint4 pk;
    pk.x = (uint32_t)f32_to_bf16_rne(f0.x) | ((uint32_t)f32_to_bf16_rne(f0.y) << 16);
    pk.y = (uint32_t)f32_to_bf16_rne(f0.z) | ((uint32_t)f32_to_bf16_rne(f0.w) << 16);
    pk.z = (uint32_t)f32_to_bf16_rne(f1.x) | ((uint32_t)f32_to_bf16_rne(f1.y) << 16);
    pk.w = (uint32_t)f32_to_bf16_rne(f1.z) | ((uint32_t)f32_to_bf16_rne(f1.w) << 16);
    *(uint4*)(out + e) = pk;
}

// ---------------------------------------------------------------------------
// Kernel 1: W[K][N] fp32  ->  Wt[N][K] bf16 (per z in {q,k,v})
// ---------------------------------------------------------------------------
__global__ __launch_bounds__(256) void wt_kernel(const float* __restrict__ Wq,
                                                 const float* __restrict__ Wk,
                                                 const float* __restrict__ Wv,
                                                 uint16_t* __restrict__ Wt) {
    const float* W = blockIdx.z == 0 ? Wq : (blockIdx.z == 1 ? Wk : Wv);
    uint16_t* out = Wt + (size_t)blockIdx.z * HIDDEN * HIDDEN;
    __shared__ float tile[64][65];
    int k0 = blockIdx.x * 64, n0 = blockIdx.y * 64;
    int r = threadIdx.x >> 6, c = threadIdx.x & 63;
    for (int it = 0; it < 16; ++it) {
        int rr = r + 4 * it;
        tile[rr][c] = W[(size_t)(k0 + rr) * HIDDEN + n0 + c];
    }
    __syncthreads();
    for (int it = 0; it < 16; ++it) {
        int rr = r + 4 * it;
        out[(size_t)(n0 + rr) * HIDDEN + k0 + c] = f32_to_bf16_rne(tile[c][rr]);
    }
}

// ---------------------------------------------------------------------------
// Kernel 2: zero the KtV accumulator (ws is poisoned 0xAA each launch)
// ---------------------------------------------------------------------------
__global__ __launch_bounds__(256) void zero_kernel(float4* __restrict__ p) {
    int i = blockIdx.x * 256 + threadIdx.x;
    p[i] = make_float4(0.f, 0.f, 0.f, 0.f);
}

// ---------------------------------------------------------------------------
// Kernel 3: projection GEMM  out[z] = Xb[z] @ Wt[z]^T(+bias)   (bf16 MFMA)
//   m97 structure: BOTH operands async global_load_lds width=16.
//   Tile 128x128, BK=64, 4 waves (2x2 of 64x64), mfma 16x16x32.
//   LDS 16B-chunk XOR swizzle: phys chunk p = logical c ^ (row&7).
// ---------------------------------------------------------------------------
__global__ __launch_bounds__(256) void proj_gemm(const uint16_t* __restrict__ Xb,
                                                 const uint16_t* __restrict__ Wt,
                                                 const float* __restrict__ Bq,
                                                 const float* __restrict__ Bk,
                                                 const float* __restrict__ Bv,
                                                 uint16_t* __restrict__ QKV) {
    const int z = blockIdx.z;
    const uint16_t* X = Xb + (size_t)z * ROWS * HIDDEN;
    const uint16_t* W = Wt + (size_t)z * HIDDEN * HIDDEN;
    const float* bias = z == 0 ? Bq : (z == 1 ? Bk : Bv);
    uint16_t* out = QKV + (size_t)z * ROWS * HIDDEN;

    __shared__ uint16_t lds[16384]; // A: [0,8192) elems, B: [8192,16384)

    const int tid = threadIdx.x;
    const int lane = tid & 63;
    const int w = tid >> 6;
    const int wm = (w >> 1) * 64;
    const int wn = (w & 1) * 64;
    const int m_lane = lane & 15;
    const int kq = lane >> 4;
    const int m0 = blockIdx.x * 128;
    const int n0 = blockIdx.y * 128;

    f32x4 acc[4][4] = {};

    for (int kb = 0; kb < HIDDEN; kb += 64) {
        // ---- stage A and B via async global->LDS, 4+4 insts/wave ----
        for (int t = 0; t < 4; ++t) {
            int gbase = (w * 4 + t) * 64;         // chunk index of lane 0
            int g = gbase + lane;                 // this lane's chunk
            int r = g >> 3;                       // LDS row
            int c = (g & 7) ^ (r & 7);            // logical k-chunk to fetch
            const uint16_t* srcA = X + (size_t)(m0 + r) * HIDDEN + kb + c * 8;
            __builtin_amdgcn_global_load_lds(
                (const __attribute__((address_space(1))) uint32_t*)srcA,
                (__attribute__((address_space(3))) uint32_t*)(&lds[gbase * 8]),
                16, 0, 0);
            const uint16_t* srcB = W + (size_t)(n0 + r) * HIDDEN + kb + c * 8;
            __builtin_amdgcn_global_load_lds(
                (const __attribute__((address_space(1))) uint32_t*)srcB,
                (__attribute__((address_space(3))) uint32_t*)(&lds[8192 + gbase * 8]),
                16, 0, 0);
        }
        __syncthreads();
        // ---- compute: 2 k-steps x 16 MFMA/wave ----
        for (int ks = 0; ks < 2; ++ks) {
            int cbase = ks * 4 + kq; // logical chunk for this lane's k-slice
            bf16x8 af[4], bfr[4];
            for (int i = 0; i < 4; ++i) {
                int r = wm + i * 16 + m_lane;
                int p = cbase ^ (r & 7);
                af[i] = *(const bf16x8*)(&lds[r * 64 + p * 8]);
            }
            for (int j = 0; j < 4; ++j) {
                int nr = wn + j * 16 + m_lane;
                int p = cbase ^ (nr & 7);
                bfr[j] = *(const bf16x8*)(&lds[8192 + nr * 64 + p * 8]);
            }
            for (int i = 0; i < 4; ++i)
                for (int j = 0; j < 4; ++j)
                    acc[i][j] = __builtin_amdgcn_mfma_f32_16x16x32_bf16(
                        af[i], bfr[j], acc[i][j], 0, 0, 0);
        }
        __syncthreads();
    }

    // ---- epilogue: +bias, store bf16. C/D: col=lane&15, row=(lane>>4)*4+reg ----
    for (int j = 0; j < 4; ++j) {
        int col = n0 + wn + j * 16 + m_lane;
        float bj = bias[col];
        for (int i = 0; i < 4; ++i) {
            int rbase = m0 + wm + i * 16 + kq * 4;
            for (int rg = 0; rg < 4; ++rg) {
                float v = acc[i][j][rg] + bj;
                out[(size_t)(rbase + rg) * HIDDEN + col] = f32_to_bf16_rne(v);
            }
        }
    }
}

// ---------------------------------------------------------------------------
// Kernel 4: M[bh] += (1/8) * K_h^T V_h  over a 128-row S chunk (atomicAdd)
//   Vectorized bf16x8 staging -> fp32 LDS, 16-row batches.
// ---------------------------------------------------------------------------
__global__ __launch_bounds__(256) void kv_kernel(const uint16_t* __restrict__ K,
                                                 const uint16_t* __restrict__ V,
                                                 float* __restrict__ M) {
    const int bh = blockIdx.x;  // b*16+h
    const int sc = blockIdx.y;  // 0..15
    const int b = bh >> 4, h = bh & 15;
    const int tid = threadIdx.x;
    const size_t base = ((size_t)b * SEQ + sc * 128) * HIDDEN + h * 64;

    __shared__ float kk[16][64];
    __shared__ float vv[16][64];
    float acc[4][4] = {};
    const int i0 = (tid >> 4) * 4, j0 = (tid & 15) * 4;

    for (int batch = 0; batch < 8; ++batch) {
        __syncthreads();
        {
            int t = tid & 127;
            int row = t >> 3, c = t & 7;
            const uint16_t* src =
                (tid < 128 ? K : V) + base + (size_t)(batch * 16 + row) * HIDDEN + c * 8;
            float* dst = (tid < 128 ? &kk[row][c * 8] : &vv[row][c * 8]);
            bf16x8 d = *(const bf16x8*)src;
            for (int e = 0; e < 8; ++e) dst[e] = bf16_to_f32((uint16_t)d[e]);
        }
        __syncthreads();
        for (int r = 0; r < 16; ++r) {
            f32x4 ka = *(const f32x4*)(&kk[r][i0]);
            f32x4 va = *(const f32x4*)(&vv[r][j0]);
            for (int a = 0; a < 4; ++a)
                for (int bb = 0; bb < 4; ++bb)
                    acc[a][bb] += ka[a] * va[bb];
        }
    }
    float* Mh = M + (size_t)bh * 4096;
    for (int a = 0; a < 4; ++a)
        for (int bb = 0; bb < 4; ++bb)
            atomicAdd(&Mh[(i0 + a) * 64 + j0 + bb], acc[a][bb] * 0.125f);
}

// ---------------------------------------------------------------------------
// Kernel 5: out[b, s, h*64+j] = sum_i Q[b,s,h*64+i] * M[bh][i][j]   (fp32 out)
//   M in LDS; each thread computes a 4x4 output patch -> 1 ds_read_b128 per i.
// ---------------------------------------------------------------------------
__global__ __launch_bounds__(256) void ctx_kernel(const uint16_t* __restrict__ Q,
                                                  const float* __restrict__ M,
                                                  float* __restrict__ out) {
    const int bh = blockIdx.x;
    const int sc = blockIdx.y; // 0..31, 64 rows each
    const int b = bh >> 4, h = bh & 15;
    const int tid = threadIdx.x;

    __shared__ float Mh[64][64]; // 16 KB
    {
        const f32x4* Ms = (const f32x4*)(M + (size_t)bh * 4096);
        f32x4* Md = (f32x4*)Mh;
        for (int t = 0; t < 4; ++t) Md[t * 256 + tid] = Ms[t * 256 + tid];
    }
    __syncthreads();

    const int r0 = (tid >> 4) * 4;   // 0..60
    const int j0 = (tid & 15) * 4;   // 0..60
    const size_t row0 = (size_t)b * SEQ + sc * 64 + r0;
    const size_t qbase = row0 * HIDDEN + h * 64;

    f32x4 acc[4] = {};
    for (int ic = 0; ic < 8; ++ic) {
        bf16x8 qv[4];
        for (int rr = 0; rr < 4; ++rr)
            qv[rr] = *(const bf16x8*)(Q + qbase + (size_t)rr * HIDDEN + ic * 8);
        for (int e = 0; e < 8; ++e) {
            f32x4 m4 = *(const f32x4*)(&Mh[ic * 8 + e][j0]);
            for (int rr = 0; rr < 4; ++rr) {
                float q = bf16_to_f32((uint16_t)qv[rr][e]);
                acc[rr] += q * m4;
            }
        }
    }
    for (int rr = 0; rr < 4; ++rr)
        *(f32x4*)(out + (row0 + rr) * HIDDEN + h * 64 + j0) = acc[rr];
}

// ---------------------------------------------------------------------------
extern "C" void kernel_launch(void* const* d_in, const int* in_sizes, int n_in,
                              void* d_out, int out_size, void* d_ws, size_t ws_size,
                              hipStream_t stream) {
    const float* Xq = (const float*)d_in[0];
    const float* Xk = (const float*)d_in[1];
    const float* Xv = (const float*)d_in[2];
    const float* Wq = (const float*)d_in[3];
    const float* Bq = (const float*)d_in[4];
    const float* Wk = (const float*)d_in[5];
    const float* Bk = (const float*)d_in[6];
    const float* Wv = (const float*)d_in[7];
    const float* Bv = (const float*)d_in[8];
    float* out = (float*)d_out;

    char* ws = (char*)d_ws;
    uint16_t* Wt = (uint16_t*)ws;                      // 6,291,456 B
    uint16_t* Xb = (uint16_t*)(ws + 6291456);          // 50,331,648 B
    uint16_t* QKV = (uint16_t*)(ws + 6291456 + 50331648); // 50,331,648 B
    float* M = (float*)(ws + 6291456 + 2 * 50331648ll);   // 1,048,576 B (total ~103 MB)

    cvt_kernel<<<dim3(3 * 4096), 256, 0, stream>>>(Xq, Xk, Xv, Xb);
    wt_kernel<<<dim3(16, 16, 3), 256, 0, stream>>>(Wq, Wk, Wv, Wt);
    zero_kernel<<<dim3(256), 256, 0, stream>>>((float4*)M);
    proj_gemm<<<dim3(64, 8, 3), 256, 0, stream>>>(Xb, Wt, Bq, Bk, Bv, QKV);

    const uint16_t* Qp = QKV;
    const uint16_t* Kp = QKV + (size_t)ROWS * HIDDEN;
    const uint16_t* Vp = QKV + 2 * (size_t)ROWS * HIDDEN;
    kv_kernel<<<dim3(64, 16), 256, 0, stream>>>(Kp, Vp, M);
    ctx_kernel<<<dim3(64, 32), 256, 0, stream>>>(Qp, M, out);
}

// Round 4
// 310.439 us; speedup vs baseline: 1.0588x; 1.0031x over previous
//
#include <hip/hip_runtime.h>
#include <stdint.h>

#define HIDDEN 1024
#define HEADS 16
#define HEAD_DIM 64
#define BATCH 4
#define SEQ 2048
#define ROWS (BATCH * SEQ) /* 8192 */

typedef float f32x4 __attribute__((ext_vector_type(4)));
typedef short bf16x8 __attribute__((ext_vector_type(8))); // 8 bf16 = 4 VGPRs

__device__ __forceinline__ uint16_t f32_to_bf16_rne(float f) {
    uint32_t u = __float_as_uint(f);
    uint32_t r = u + 0x7FFFu + ((u >> 16) & 1u);
    return (uint16_t)(r >> 16);
}
__device__ __forceinline__ float bf16_to_f32(uint16_t u) {
    return __uint_as_float(((uint32_t)u) << 16);
}

// ---------------------------------------------------------------------------
// Kernel 0: convert X (q,k,v inputs) fp32 -> bf16, streaming.
// First 256 blocks also zero the 1 MB M accumulator (ws is 0xAA-poisoned).
// ---------------------------------------------------------------------------
__global__ __launch_bounds__(256) void cvt_kernel(const float* __restrict__ Xq,
                                                  const float* __restrict__ Xk,
                                                  const float* __restrict__ Xv,
                                                  uint16_t* __restrict__ Xb,
                                                  float4* __restrict__ M) {
    if (blockIdx.x < 256)
        M[blockIdx.x * 256 + threadIdx.x] = make_float4(0.f, 0.f, 0.f, 0.f);
    int z = blockIdx.x >> 12;
    const float* X = z == 0 ? Xq : (z == 1 ? Xk : Xv);
    uint16_t* out = Xb + (size_t)z * ROWS * HIDDEN;
    size_t e = ((size_t)(blockIdx.x & 4095) * 256 + threadIdx.x) * 8;
    float4 f0 = *(const float4*)(X + e);
    float4 f1 = *(const float4*)(X + e + 4);
    uint4 pk;
    pk.x = (uint32_t)f32_to_bf16_rne(f0.x) | ((uint32_t)f32_to_bf16_rne(f0.y) << 16);
    pk.y = (uint32_t)f32_to_bf16_rne(f0.z) | ((uint32_t)f32_to_bf16_rne(f0.w) << 16);
    pk.z = (uint32_t)f32_to_bf16_rne(f1.x) | ((uint32_t)f32_to_bf16_rne(f1.y) << 16);
    pk.w = (uint32_t)f32_to_bf16_rne(f1.z) | ((uint32_t)f32_to_bf16_rne(f1.w) << 16);
    *(uint4*)(out + e) = pk;
}

// ---------------------------------------------------------------------------
// Kernel 1: W[K][N] fp32 -> Wt[N][K] bf16, z in {Wk, Wv} only (Wq stays fp32)
// ---------------------------------------------------------------------------
__global__ __launch_bounds__(256) void wt_kernel(const float* __restrict__ Wk,
                                                 const float* __restrict__ Wv,
                                                 uint16_t* __restrict__ Wt) {
    const float* W = blockIdx.z == 0 ? Wk : Wv;
    uint16_t* out = Wt + (size_t)blockIdx.z * HIDDEN * HIDDEN;
    __shared__ float tile[64][65];
    int k0 = blockIdx.x * 64, n0 = blockIdx.y * 64;
    int r = threadIdx.x >> 6, c = threadIdx.x & 63;
    for (int it = 0; it < 16; ++it) {
        int rr = r + 4 * it;
        tile[rr][c] = W[(size_t)(k0 + rr) * HIDDEN + n0 + c];
    }
    __syncthreads();
    for (int it = 0; it < 16; ++it) {
        int rr = r + 4 * it;
        out[(size_t)(n0 + rr) * HIDDEN + k0 + c] = f32_to_bf16_rne(tile[c][rr]);
    }
}

// ---------------------------------------------------------------------------
// Kernel 2: K/V projection GEMM  KV[z] = Xkv[z] @ Wt[z]^T + bias  (bf16 MFMA)
//   m97 structure, both operands async global_load_lds w=16, XOR-swizzled LDS.
// ---------------------------------------------------------------------------
__global__ __launch_bounds__(256) void proj_gemm(const uint16_t* __restrict__ Xkv,
                                                 const uint16_t* __restrict__ Wt,
                                                 const float* __restrict__ Bk,
                                                 const float* __restrict__ Bv,
                                                 uint16_t* __restrict__ KV) {
    const int z = blockIdx.z; // 0=K, 1=V
    const uint16_t* X = Xkv + (size_t)z * ROWS * HIDDEN;
    const uint16_t* W = Wt + (size_t)z * HIDDEN * HIDDEN;
    const float* bias = z == 0 ? Bk : Bv;
    uint16_t* out = KV + (size_t)z * ROWS * HIDDEN;

    __shared__ uint16_t lds[16384]; // A: [0,8192), B: [8192,16384)

    const int tid = threadIdx.x;
    const int lane = tid & 63;
    const int w = tid >> 6;
    const int wm = (w >> 1) * 64;
    const int wn = (w & 1) * 64;
    const int m_lane = lane & 15;
    const int kq = lane >> 4;
    const int m0 = blockIdx.x * 128;
    const int n0 = blockIdx.y * 128;

    f32x4 acc[4][4] = {};

    for (int kb = 0; kb < HIDDEN; kb += 64) {
        for (int t = 0; t < 4; ++t) {
            int gbase = (w * 4 + t) * 64;
            int g = gbase + lane;
            int r = g >> 3;
            int c = (g & 7) ^ (r & 7);
            const uint16_t* srcA = X + (size_t)(m0 + r) * HIDDEN + kb + c * 8;
            __builtin_amdgcn_global_load_lds(
                (const __attribute__((address_space(1))) uint32_t*)srcA,
                (__attribute__((address_space(3))) uint32_t*)(&lds[gbase * 8]),
                16, 0, 0);
            const uint16_t* srcB = W + (size_t)(n0 + r) * HIDDEN + kb + c * 8;
            __builtin_amdgcn_global_load_lds(
                (const __attribute__((address_space(1))) uint32_t*)srcB,
                (__attribute__((address_space(3))) uint32_t*)(&lds[8192 + gbase * 8]),
                16, 0, 0);
        }
        __syncthreads();
        for (int ks = 0; ks < 2; ++ks) {
            int cbase = ks * 4 + kq;
            bf16x8 af[4], bfr[4];
            for (int i = 0; i < 4; ++i) {
                int r = wm + i * 16 + m_lane;
                int p = cbase ^ (r & 7);
                af[i] = *(const bf16x8*)(&lds[r * 64 + p * 8]);
            }
            for (int j = 0; j < 4; ++j) {
                int nr = wn + j * 16 + m_lane;
                int p = cbase ^ (nr & 7);
                bfr[j] = *(const bf16x8*)(&lds[8192 + nr * 64 + p * 8]);
            }
            for (int i = 0; i < 4; ++i)
                for (int j = 0; j < 4; ++j)
                    acc[i][j] = __builtin_amdgcn_mfma_f32_16x16x32_bf16(
                        af[i], bfr[j], acc[i][j], 0, 0, 0);
        }
        __syncthreads();
    }

    for (int j = 0; j < 4; ++j) {
        int col = n0 + wn + j * 16 + m_lane;
        float bj = bias[col];
        for (int i = 0; i < 4; ++i) {
            int rbase = m0 + wm + i * 16 + kq * 4;
            for (int rg = 0; rg < 4; ++rg) {
                float v = acc[i][j][rg] + bj;
                out[(size_t)(rbase + rg) * HIDDEN + col] = f32_to_bf16_rne(v);
            }
        }
    }
}

// ---------------------------------------------------------------------------
// Kernel 3: M[bh] += (1/8) * K_h^T V_h  over a 128-row S chunk (atomicAdd)
// ---------------------------------------------------------------------------
__global__ __launch_bounds__(256) void kv_kernel(const uint16_t* __restrict__ KV,
                                                 float* __restrict__ M) {
    const uint16_t* K = KV;
    const uint16_t* V = KV + (size_t)ROWS * HIDDEN;
    const int bh = blockIdx.x;  // b*16+h
    const int sc = blockIdx.y;
    const int b = bh >> 4, h = bh & 15;
    const int tid = threadIdx.x;
    const size_t base = ((size_t)b * SEQ + sc * 128) * HIDDEN + h * 64;

    __shared__ float kk[16][64];
    __shared__ float vv[16][64];
    float acc[4][4] = {};
    const int i0 = (tid >> 4) * 4, j0 = (tid & 15) * 4;

    for (int batch = 0; batch < 8; ++batch) {
        __syncthreads();
        {
            int t = tid & 127;
            int row = t >> 3, c = t & 7;
            const uint16_t* src =
                (tid < 128 ? K : V) + base + (size_t)(batch * 16 + row) * HIDDEN + c * 8;
            float* dst = (tid < 128 ? &kk[row][c * 8] : &vv[row][c * 8]);
            bf16x8 d = *(const bf16x8*)src;
            for (int e = 0; e < 8; ++e) dst[e] = bf16_to_f32((uint16_t)d[e]);
        }
        __syncthreads();
        for (int r = 0; r < 16; ++r) {
            f32x4 ka = *(const f32x4*)(&kk[r][i0]);
            f32x4 va = *(const f32x4*)(&vv[r][j0]);
            for (int a = 0; a < 4; ++a)
                for (int bb = 0; bb < 4; ++bb)
                    acc[a][bb] += ka[a] * va[bb];
        }
    }
    float* Mh = M + (size_t)bh * 4096;
    for (int a = 0; a < 4; ++a)
        for (int bb = 0; bb < 4; ++bb)
            atomicAdd(&Mh[(i0 + a) * 64 + j0 + bb], acc[a][bb] * 0.125f);
}

// ---------------------------------------------------------------------------
// Kernel 4: fold M into weights — PER BATCH (M differs per bh!).
//   W't[b][n=h*64+j][k=r] = sum_i Wq[r][h*64+i] * M[b*16+h][i][j]   (bf16)
//   b'[b][n]              = sum_i bq[h*64+i]    * M[b*16+h][i][j]   (fp32)
// grid (16 h, 16 rc, 4 b), block 256.
// ---------------------------------------------------------------------------
__global__ __launch_bounds__(256) void wprime_kernel(const float* __restrict__ Wq,
                                                     const float* __restrict__ bq,
                                                     const float* __restrict__ M,
                                                     uint16_t* __restrict__ Wpt,
                                                     float* __restrict__ bp) {
    const int h = blockIdx.x;
    const int r0 = blockIdx.y * 64;
    const int b = blockIdx.z;
    const int tid = threadIdx.x;

    __shared__ float Mh[64][65];
    __shared__ float Wl[64][65];
    for (int it = 0; it < 16; ++it) {
        int e = it * 256 + tid;
        int a = e >> 6, c = e & 63;
        Mh[a][c] = M[((size_t)(b * 16 + h)) * 4096 + e];
        Wl[a][c] = Wq[(size_t)(r0 + a) * HIDDEN + h * 64 + c];
    }
    __syncthreads();

    const int r = tid & 63;
    const int jbase = tid >> 6; // 0..3
    float acc[16] = {};
    for (int i = 0; i < 64; ++i) {
        float wv = Wl[r][i];
        for (int jj = 0; jj < 16; ++jj)
            acc[jj] += wv * Mh[i][jbase + 4 * jj];
    }
    uint16_t* Wb = Wpt + (size_t)b * HIDDEN * HIDDEN;
    for (int jj = 0; jj < 16; ++jj) {
        int n = h * 64 + jbase + 4 * jj;
        Wb[(size_t)n * HIDDEN + r0 + r] = f32_to_bf16_rne(acc[jj]);
    }

    if (blockIdx.y == 0 && tid < 64) {
        int j = tid;
        float s = 0.f;
        for (int i = 0; i < 64; ++i) s += bq[h * 64 + i] * Mh[i][j];
        bp[b * HIDDEN + h * 64 + j] = s;
    }
}

// ---------------------------------------------------------------------------
// Kernel 5: out = Xq @ W'_b^T + b'_b   (fp32 output to d_out)
//   batch = m0 >> 11 (each 128-row tile lies in one batch).
// ---------------------------------------------------------------------------
__global__ __launch_bounds__(256) void final_gemm(const uint16_t* __restrict__ Xq,
                                                  const uint16_t* __restrict__ Wpt,
                                                  const float* __restrict__ bp,
                                                  float* __restrict__ out) {
    __shared__ uint16_t lds[16384];

    const int tid = threadIdx.x;
    const int lane = tid & 63;
    const int w = tid >> 6;
    const int wm = (w >> 1) * 64;
    const int wn = (w & 1) * 64;
    const int m_lane = lane & 15;
    const int kq = lane >> 4;
    const int m0 = blockIdx.x * 128;
    const int n0 = blockIdx.y * 128;
    const int batch = m0 >> 11;
    const uint16_t* W = Wpt + (size_t)batch * HIDDEN * HIDDEN;
    const float* bias = bp + batch * HIDDEN;

    f32x4 acc[4][4] = {};

    for (int kb = 0; kb < HIDDEN; kb += 64) {
        for (int t = 0; t < 4; ++t) {
            int gbase = (w * 4 + t) * 64;
            int g = gbase + lane;
            int r = g >> 3;
            int c = (g & 7) ^ (r & 7);
            const uint16_t* srcA = Xq + (size_t)(m0 + r) * HIDDEN + kb + c * 8;
            __builtin_amdgcn_global_load_lds(
                (const __attribute__((address_space(1))) uint32_t*)srcA,
                (__attribute__((address_space(3))) uint32_t*)(&lds[gbase * 8]),
                16, 0, 0);
            const uint16_t* srcB = W + (size_t)(n0 + r) * HIDDEN + kb + c * 8;
            __builtin_amdgcn_global_load_lds(
                (const __attribute__((address_space(1))) uint32_t*)srcB,
                (__attribute__((address_space(3))) uint32_t*)(&lds[8192 + gbase * 8]),
                16, 0, 0);
        }
        __syncthreads();
        for (int ks = 0; ks < 2; ++ks) {
            int cbase = ks * 4 + kq;
            bf16x8 af[4], bfr[4];
            for (int i = 0; i < 4; ++i) {
                int r = wm + i * 16 + m_lane;
                int p = cbase ^ (r & 7);
                af[i] = *(const bf16x8*)(&lds[r * 64 + p * 8]);
            }
            for (int j = 0; j < 4; ++j) {
                int nr = wn + j * 16 + m_lane;
                int p = cbase ^ (nr & 7);
                bfr[j] = *(const bf16x8*)(&lds[8192 + nr * 64 + p * 8]);
            }
            for (int i = 0; i < 4; ++i)
                for (int j = 0; j < 4; ++j)
                    acc[i][j] = __builtin_amdgcn_mfma_f32_16x16x32_bf16(
                        af[i], bfr[j], acc[i][j], 0, 0, 0);
        }
        __syncthreads();
    }

    for (int j = 0; j < 4; ++j) {
        int col = n0 + wn + j * 16 + m_lane;
        float bj = bias[col];
        for (int i = 0; i < 4; ++i) {
            int rbase = m0 + wm + i * 16 + kq * 4;
            for (int rg = 0; rg < 4; ++rg)
                out[(size_t)(rbase + rg) * HIDDEN + col] = acc[i][j][rg] + bj;
        }
    }
}

// ---------------------------------------------------------------------------
extern "C" void kernel_launch(void* const* d_in, const int* in_sizes, int n_in,
                              void* d_out, int out_size, void* d_ws, size_t ws_size,
                              hipStream_t stream) {
    const float* Xq = (const float*)d_in[0];
    const float* Xk = (const float*)d_in[1];
    const float* Xv = (const float*)d_in[2];
    const float* Wq = (const float*)d_in[3];
    const float* Bq = (const float*)d_in[4];
    const float* Wk = (const float*)d_in[5];
    const float* Bk = (const float*)d_in[6];
    const float* Wv = (const float*)d_in[7];
    const float* Bv = (const float*)d_in[8];
    float* out = (float*)d_out;

    char* ws = (char*)d_ws;
    uint16_t* Xb = (uint16_t*)ws;                        // 50,331,648 B (Xq,Xk,Xv bf16)
    uint16_t* KV = (uint16_t*)(ws + 50331648);           // 33,554,432 B (K,V bf16)
    uint16_t* Wt = (uint16_t*)(ws + 83886080);           //  4,194,304 B (Wk,Wv bf16 T)
    float* M = (float*)(ws + 88080384);                  //  1,048,576 B
    uint16_t* Wpt = (uint16_t*)(ws + 89128960);          //  8,388,608 B (4 x W'_b)
    float* bp = (float*)(ws + 97517568);                 //     16,384 B (~97.5 MB)

    cvt_kernel<<<dim3(3 * 4096), 256, 0, stream>>>(Xq, Xk, Xv, Xb, (float4*)M);
    wt_kernel<<<dim3(16, 16, 2), 256, 0, stream>>>(Wk, Wv, Wt);

    const uint16_t* Xkv = Xb + (size_t)ROWS * HIDDEN;
    proj_gemm<<<dim3(64, 8, 2), 256, 0, stream>>>(Xkv, Wt, Bk, Bv, KV);
    kv_kernel<<<dim3(64, 16), 256, 0, stream>>>(KV, M);
    wprime_kernel<<<dim3(16, 16, 4), 256, 0, stream>>>(Wq, Bq, M, Wpt, bp);
    final_gemm<<<dim3(64, 8), 256, 0, stream>>>(Xb, Wpt, bp, out);
}

// Round 5
// 271.259 us; speedup vs baseline: 1.2117x; 1.1444x over previous
//
#include <hip/hip_runtime.h>
#include <stdint.h>

#define HIDDEN 1024
#define HEADS 16
#define HEAD_DIM 64
#define BATCH 4
#define SEQ 2048
#define ROWS (BATCH * SEQ) /* 8192 */

typedef float f32x4 __attribute__((ext_vector_type(4)));
typedef short bf16x8 __attribute__((ext_vector_type(8))); // 8 bf16 = 4 VGPRs

__device__ __forceinline__ uint16_t f32_to_bf16_rne(float f) {
    uint32_t u = __float_as_uint(f);
    uint32_t r = u + 0x7FFFu + ((u >> 16) & 1u);
    return (uint16_t)(r >> 16);
}
__device__ __forceinline__ float bf16_to_f32(uint16_t u) {
    return __uint_as_float(((uint32_t)u) << 16);
}

// ---------------------------------------------------------------------------
// Kernel 0: convert X (q,k,v inputs) fp32 -> bf16, streaming.
// ---------------------------------------------------------------------------
__global__ __launch_bounds__(256) void cvt_kernel(const float* __restrict__ Xq,
                                                  const float* __restrict__ Xk,
                                                  const float* __restrict__ Xv,
                                                  uint16_t* __restrict__ Xb) {
    int z = blockIdx.x >> 12;
    const float* X = z == 0 ? Xq : (z == 1 ? Xk : Xv);
    uint16_t* out = Xb + (size_t)z * ROWS * HIDDEN;
    size_t e = ((size_t)(blockIdx.x & 4095) * 256 + threadIdx.x) * 8;
    float4 f0 = *(const float4*)(X + e);
    float4 f1 = *(const float4*)(X + e + 4);
    uint4 pk;
    pk.x = (uint32_t)f32_to_bf16_rne(f0.x) | ((uint32_t)f32_to_bf16_rne(f0.y) << 16);
    pk.y = (uint32_t)f32_to_bf16_rne(f0.z) | ((uint32_t)f32_to_bf16_rne(f0.w) << 16);
    pk.z = (uint32_t)f32_to_bf16_rne(f1.x) | ((uint32_t)f32_to_bf16_rne(f1.y) << 16);
    pk.w = (uint32_t)f32_to_bf16_rne(f1.z) | ((uint32_t)f32_to_bf16_rne(f1.w) << 16);
    *(uint4*)(out + e) = pk;
}

// ---------------------------------------------------------------------------
// Kernel 1: W[K][N] fp32 -> Wt[N][K] bf16, z in {Wk, Wv} only (Wq stays fp32)
// ---------------------------------------------------------------------------
__global__ __launch_bounds__(256) void wt_kernel(const float* __restrict__ Wk,
                                                 const float* __restrict__ Wv,
                                                 uint16_t* __restrict__ Wt) {
    const float* W = blockIdx.z == 0 ? Wk : Wv;
    uint16_t* out = Wt + (size_t)blockIdx.z * HIDDEN * HIDDEN;
    __shared__ float tile[64][65];
    int k0 = blockIdx.x * 64, n0 = blockIdx.y * 64;
    int r = threadIdx.x >> 6, c = threadIdx.x & 63;
    for (int it = 0; it < 16; ++it) {
        int rr = r + 4 * it;
        tile[rr][c] = W[(size_t)(k0 + rr) * HIDDEN + n0 + c];
    }
    __syncthreads();
    for (int it = 0; it < 16; ++it) {
        int rr = r + 4 * it;
        out[(size_t)(n0 + rr) * HIDDEN + k0 + c] = f32_to_bf16_rne(tile[c][rr]);
    }
}

// ---------------------------------------------------------------------------
// Kernel 2: K/V projection GEMM  KV[z] = Xkv[z] @ Wt[z]^T + bias  (bf16 MFMA)
//   m97 structure, both operands async global_load_lds w=16, XOR-swizzled LDS.
// ---------------------------------------------------------------------------
__global__ __launch_bounds__(256) void proj_gemm(const uint16_t* __restrict__ Xkv,
                                                 const uint16_t* __restrict__ Wt,
                                                 const float* __restrict__ Bk,
                                                 const float* __restrict__ Bv,
                                                 uint16_t* __restrict__ KV) {
    const int z = blockIdx.z; // 0=K, 1=V
    const uint16_t* X = Xkv + (size_t)z * ROWS * HIDDEN;
    const uint16_t* W = Wt + (size_t)z * HIDDEN * HIDDEN;
    const float* bias = z == 0 ? Bk : Bv;
    uint16_t* out = KV + (size_t)z * ROWS * HIDDEN;

    __shared__ uint16_t lds[16384]; // A: [0,8192), B: [8192,16384)

    const int tid = threadIdx.x;
    const int lane = tid & 63;
    const int w = tid >> 6;
    const int wm = (w >> 1) * 64;
    const int wn = (w & 1) * 64;
    const int m_lane = lane & 15;
    const int kq = lane >> 4;
    const int m0 = blockIdx.x * 128;
    const int n0 = blockIdx.y * 128;

    f32x4 acc[4][4] = {};

    for (int kb = 0; kb < HIDDEN; kb += 64) {
        for (int t = 0; t < 4; ++t) {
            int gbase = (w * 4 + t) * 64;
            int g = gbase + lane;
            int r = g >> 3;
            int c = (g & 7) ^ (r & 7);
            const uint16_t* srcA = X + (size_t)(m0 + r) * HIDDEN + kb + c * 8;
            __builtin_amdgcn_global_load_lds(
                (const __attribute__((address_space(1))) uint32_t*)srcA,
                (__attribute__((address_space(3))) uint32_t*)(&lds[gbase * 8]),
                16, 0, 0);
            const uint16_t* srcB = W + (size_t)(n0 + r) * HIDDEN + kb + c * 8;
            __builtin_amdgcn_global_load_lds(
                (const __attribute__((address_space(1))) uint32_t*)srcB,
                (__attribute__((address_space(3))) uint32_t*)(&lds[8192 + gbase * 8]),
                16, 0, 0);
        }
        __syncthreads();
        for (int ks = 0; ks < 2; ++ks) {
            int cbase = ks * 4 + kq;
            bf16x8 af[4], bfr[4];
            for (int i = 0; i < 4; ++i) {
                int r = wm + i * 16 + m_lane;
                int p = cbase ^ (r & 7);
                af[i] = *(const bf16x8*)(&lds[r * 64 + p * 8]);
            }
            for (int j = 0; j < 4; ++j) {
                int nr = wn + j * 16 + m_lane;
                int p = cbase ^ (nr & 7);
                bfr[j] = *(const bf16x8*)(&lds[8192 + nr * 64 + p * 8]);
            }
            for (int i = 0; i < 4; ++i)
                for (int j = 0; j < 4; ++j)
                    acc[i][j] = __builtin_amdgcn_mfma_f32_16x16x32_bf16(
                        af[i], bfr[j], acc[i][j], 0, 0, 0);
        }
        __syncthreads();
    }

    for (int j = 0; j < 4; ++j) {
        int col = n0 + wn + j * 16 + m_lane;
        float bj = bias[col];
        for (int i = 0; i < 4; ++i) {
            int rbase = m0 + wm + i * 16 + kq * 4;
            for (int rg = 0; rg < 4; ++rg) {
                float v = acc[i][j][rg] + bj;
                out[(size_t)(rbase + rg) * HIDDEN + col] = f32_to_bf16_rne(v);
            }
        }
    }
}

// ---------------------------------------------------------------------------
// Kernel 3: P[bh][sc] = (1/8) * K_h^T V_h over a 256-row S chunk.
//   NO atomics: each block owns a private 64x64 fp32 partial.
// ---------------------------------------------------------------------------
__global__ __launch_bounds__(256) void kv_kernel(const uint16_t* __restrict__ KV,
                                                 float* __restrict__ P) {
    const uint16_t* K = KV;
    const uint16_t* V = KV + (size_t)ROWS * HIDDEN;
    const int bh = blockIdx.x;  // b*16+h
    const int sc = blockIdx.y;  // 0..7, 256 rows each
    const int b = bh >> 4, h = bh & 15;
    const int tid = threadIdx.x;
    const size_t base = ((size_t)b * SEQ + sc * 256) * HIDDEN + h * 64;

    __shared__ float kk[16][64];
    __shared__ float vv[16][64];
    float acc[4][4] = {};
    const int i0 = (tid >> 4) * 4, j0 = (tid & 15) * 4;

    for (int batch = 0; batch < 16; ++batch) {
        __syncthreads();
        {
            int t = tid & 127;
            int row = t >> 3, c = t & 7;
            const uint16_t* src =
                (tid < 128 ? K : V) + base + (size_t)(batch * 16 + row) * HIDDEN + c * 8;
            float* dst = (tid < 128 ? &kk[row][c * 8] : &vv[row][c * 8]);
            bf16x8 d = *(const bf16x8*)src;
            for (int e = 0; e < 8; ++e) dst[e] = bf16_to_f32((uint16_t)d[e]);
        }
        __syncthreads();
        for (int r = 0; r < 16; ++r) {
            f32x4 ka = *(const f32x4*)(&kk[r][i0]);
            f32x4 va = *(const f32x4*)(&vv[r][j0]);
            for (int a = 0; a < 4; ++a)
                for (int bb = 0; bb < 4; ++bb)
                    acc[a][bb] += ka[a] * va[bb];
        }
    }
    float* Pp = P + ((size_t)bh * 8 + sc) * 4096;
    for (int a = 0; a < 4; ++a) {
        f32x4 row;
        for (int bb = 0; bb < 4; ++bb) row[bb] = acc[a][bb] * 0.125f;
        *(f32x4*)(&Pp[(i0 + a) * 64 + j0]) = row;
    }
}

// ---------------------------------------------------------------------------
// Kernel 4: fold M into weights — PER BATCH. Sums the 8 kv partials inline.
//   W't[b][n=h*64+j][k=r] = sum_i Wq[r][h*64+i] * M[b*16+h][i][j]   (bf16)
//   b'[b][n]              = sum_i bq[h*64+i]    * M[b*16+h][i][j]   (fp32)
// grid (16 h, 16 rc, 4 b), block 256.
// ---------------------------------------------------------------------------
__global__ __launch_bounds__(256) void wprime_kernel(const float* __restrict__ Wq,
                                                     const float* __restrict__ bq,
                                                     const float* __restrict__ P,
                                                     uint16_t* __restrict__ Wpt,
                                                     float* __restrict__ bp) {
    const int h = blockIdx.x;
    const int r0 = blockIdx.y * 64;
    const int b = blockIdx.z;
    const int tid = threadIdx.x;

    __shared__ float Mh[64][65];
    __shared__ float Wl[64][65];
    const float* Pp = P + ((size_t)(b * 16 + h)) * 8 * 4096;
    for (int it = 0; it < 16; ++it) {
        int e = it * 256 + tid;
        int a = e >> 6, c = e & 63;
        float s = 0.f;
        for (int sc = 0; sc < 8; ++sc) s += Pp[sc * 4096 + e];
        Mh[a][c] = s;
        Wl[a][c] = Wq[(size_t)(r0 + a) * HIDDEN + h * 64 + c];
    }
    __syncthreads();

    const int r = tid & 63;
    const int jbase = tid >> 6; // 0..3
    float acc[16] = {};
    for (int i = 0; i < 64; ++i) {
        float wv = Wl[r][i];
        for (int jj = 0; jj < 16; ++jj)
            acc[jj] += wv * Mh[i][jbase + 4 * jj];
    }
    uint16_t* Wb = Wpt + (size_t)b * HIDDEN * HIDDEN;
    for (int jj = 0; jj < 16; ++jj) {
        int n = h * 64 + jbase + 4 * jj;
        Wb[(size_t)n * HIDDEN + r0 + r] = f32_to_bf16_rne(acc[jj]);
    }

    if (blockIdx.y == 0 && tid < 64) {
        int j = tid;
        float s = 0.f;
        for (int i = 0; i < 64; ++i) s += bq[h * 64 + i] * Mh[i][j];
        bp[b * HIDDEN + h * 64 + j] = s;
    }
}

// ---------------------------------------------------------------------------
// Kernel 5: out = Xq @ W'_b^T + b'_b   (fp32 output to d_out)
//   batch = m0 >> 11 (each 128-row tile lies in one batch).
// ---------------------------------------------------------------------------
__global__ __launch_bounds__(256) void final_gemm(const uint16_t* __restrict__ Xq,
                                                  const uint16_t* __restrict__ Wpt,
                                                  const float* __restrict__ bp,
                                                  float* __restrict__ out) {
    __shared__ uint16_t lds[16384];

    const int tid = threadIdx.x;
    const int lane = tid & 63;
    const int w = tid >> 6;
    const int wm = (w >> 1) * 64;
    const int wn = (w & 1) * 64;
    const int m_lane = lane & 15;
    const int kq = lane >> 4;
    const int m0 = blockIdx.x * 128;
    const int n0 = blockIdx.y * 128;
    const int batch = m0 >> 11;
    const uint16_t* W = Wpt + (size_t)batch * HIDDEN * HIDDEN;
    const float* bias = bp + batch * HIDDEN;

    f32x4 acc[4][4] = {};

    for (int kb = 0; kb < HIDDEN; kb += 64) {
        for (int t = 0; t < 4; ++t) {
            int gbase = (w * 4 + t) * 64;
            int g = gbase + lane;
            int r = g >> 3;
            int c = (g & 7) ^ (r & 7);
            const uint16_t* srcA = Xq + (size_t)(m0 + r) * HIDDEN + kb + c * 8;
            __builtin_amdgcn_global_load_lds(
                (const __attribute__((address_space(1))) uint32_t*)srcA,
                (__attribute__((address_space(3))) uint32_t*)(&lds[gbase * 8]),
                16, 0, 0);
            const uint16_t* srcB = W + (size_t)(n0 + r) * HIDDEN + kb + c * 8;
            __builtin_amdgcn_global_load_lds(
                (const __attribute__((address_space(1))) uint32_t*)srcB,
                (__attribute__((address_space(3))) uint32_t*)(&lds[8192 + gbase * 8]),
                16, 0, 0);
        }
        __syncthreads();
        for (int ks = 0; ks < 2; ++ks) {
            int cbase = ks * 4 + kq;
            bf16x8 af[4], bfr[4];
            for (int i = 0; i < 4; ++i) {
                int r = wm + i * 16 + m_lane;
                int p = cbase ^ (r & 7);
                af[i] = *(const bf16x8*)(&lds[r * 64 + p * 8]);
            }
            for (int j = 0; j < 4; ++j) {
                int nr = wn + j * 16 + m_lane;
                int p = cbase ^ (nr & 7);
                bfr[j] = *(const bf16x8*)(&lds[8192 + nr * 64 + p * 8]);
            }
            for (int i = 0; i < 4; ++i)
                for (int j = 0; j < 4; ++j)
                    acc[i][j] = __builtin_amdgcn_mfma_f32_16x16x32_bf16(
                        af[i], bfr[j], acc[i][j], 0, 0, 0);
        }
        __syncthreads();
    }

    for (int j = 0; j < 4; ++j) {
        int col = n0 + wn + j * 16 + m_lane;
        float bj = bias[col];
        for (int i = 0; i < 4; ++i) {
            int rbase = m0 + wm + i * 16 + kq * 4;
            for (int rg = 0; rg < 4; ++rg)
                out[(size_t)(rbase + rg) * HIDDEN + col] = acc[i][j][rg] + bj;
        }
    }
}

// ---------------------------------------------------------------------------
extern "C" void kernel_launch(void* const* d_in, const int* in_sizes, int n_in,
                              void* d_out, int out_size, void* d_ws, size_t ws_size,
                              hipStream_t stream) {
    const float* Xq = (const float*)d_in[0];
    const float* Xk = (const float*)d_in[1];
    const float* Xv = (const float*)d_in[2];
    const float* Wq = (const float*)d_in[3];
    const float* Bq = (const float*)d_in[4];
    const float* Wk = (const float*)d_in[5];
    const float* Bk = (const float*)d_in[6];
    const float* Wv = (const float*)d_in[7];
    const float* Bv = (const float*)d_in[8];
    float* out = (float*)d_out;

    char* ws = (char*)d_ws;
    uint16_t* Xb = (uint16_t*)ws;                        // 50,331,648 B (Xq,Xk,Xv bf16)
    uint16_t* KV = (uint16_t*)(ws + 50331648);           // 33,554,432 B (K,V bf16)
    uint16_t* Wt = (uint16_t*)(ws + 83886080);           //  4,194,304 B (Wk,Wv bf16 T)
    float* P = (float*)(ws + 88080384);                  //  8,388,608 B (64bh x 8sc x 4096)
    uint16_t* Wpt = (uint16_t*)(ws + 96468992);          //  8,388,608 B (4 x W'_b)
    float* bp = (float*)(ws + 104857600);                //     16,384 B (~100 MB)

    cvt_kernel<<<dim3(3 * 4096), 256, 0, stream>>>(Xq, Xk, Xv, Xb);
    wt_kernel<<<dim3(16, 16, 2), 256, 0, stream>>>(Wk, Wv, Wt);

    const uint16_t* Xkv = Xb + (size_t)ROWS * HIDDEN;
    proj_gemm<<<dim3(64, 8, 2), 256, 0, stream>>>(Xkv, Wt, Bk, Bv, KV);
    kv_kernel<<<dim3(64, 8), 256, 0, stream>>>(KV, P);
    wprime_kernel<<<dim3(16, 16, 4), 256, 0, stream>>>(Wq, Bq, P, Wpt, bp);
    final_gemm<<<dim3(64, 8), 256, 0, stream>>>(Xb, Wpt, bp, out);
}